// Round 10
// baseline (1431.675 us; speedup 1.0000x reference)
//
#include <hip/hip_runtime.h>

typedef unsigned short ushort_t;
typedef unsigned int uint_t;

static __device__ __forceinline__ ushort_t f2bf(float f) {
    uint_t u = __float_as_uint(f);
    uint_t r = (u + 0x7FFFu + ((u >> 16) & 1u)) >> 16;   // RNE
    return (ushort_t)r;
}
static __device__ __forceinline__ float bf2f(ushort_t u) {
    return __uint_as_float(((uint_t)u) << 16);
}
static __device__ __forceinline__ float bf2f_lo(uint_t u) {
    return __uint_as_float(u << 16);
}
static __device__ __forceinline__ float bf2f_hi(uint_t u) {
    return __uint_as_float(u & 0xffff0000u);
}
static __device__ __forceinline__ uint_t pack2(float lo, float hi) {
    return (uint_t)f2bf(lo) | ((uint_t)f2bf(hi) << 16);
}

// score contribution of one edge: relu(A + B + e@Wc) . w2  (4 features/lane)
static __device__ __forceinline__ float edge_p2(
    uint_t ax, uint_t ay, float4 brow, float ex, float ey,
    float4 wc0, float4 wc1, float4 w2v)
{
    float z0 = bf2f_lo(ax) + brow.x + ex*wc0.x + ey*wc1.x; z0 = fmaxf(z0, 0.f);
    float z1 = bf2f_hi(ax) + brow.y + ex*wc0.y + ey*wc1.y; z1 = fmaxf(z1, 0.f);
    float z2 = bf2f_lo(ay) + brow.z + ex*wc0.z + ey*wc1.z; z2 = fmaxf(z2, 0.f);
    float z3 = bf2f_hi(ay) + brow.w + ex*wc0.w + ey*wc1.w; z3 = fmaxf(z3, 0.f);
    return z0*w2v.x + z1*w2v.y + z2*w2v.z + z3*w2v.w;
}

#define RED16(p) { p += __shfl_xor(p,1); p += __shfl_xor(p,2); \
                   p += __shfl_xor(p,4); p += __shfl_xor(p,8); }

// ---------------- CSR build ----------------
__global__ __launch_bounds__(256) void k_count(
    const int* __restrict__ dst, int* __restrict__ deg, int E)
{
    int e = blockIdx.x * 256 + threadIdx.x;
    if (e < E) atomicAdd(&deg[dst[e]], 1);
}

static __device__ __forceinline__ int deg_bucket(int d) {
    return d >= 63 ? 0 : (63 - d);
}

// per-block (1024) exclusive scan + degree-bucket histogram (fused)
__global__ __launch_bounds__(1024) void k_scanA(
    const int* __restrict__ deg, int* __restrict__ partial,
    int* __restrict__ bsum, int* __restrict__ bcnt, int N)
{
    __shared__ int wsum[16];
    __shared__ int hist[64];
    int tid = threadIdx.x, lane = tid & 63, wid = tid >> 6;
    if (tid < 64) hist[tid] = 0;
    __syncthreads();
    int idx = blockIdx.x * 1024 + tid;
    int v = (idx < N) ? deg[idx] : 0;
    if (idx < N) atomicAdd(&hist[deg_bucket(v)], 1);
    int x = v;
#pragma unroll
    for (int o = 1; o < 64; o <<= 1) {
        int t = __shfl_up(x, o, 64);
        if (lane >= o) x += t;
    }
    if (lane == 63) wsum[wid] = x;
    __syncthreads();
    if (wid == 0) {
        int s = (lane < 16) ? wsum[lane] : 0;
#pragma unroll
        for (int o = 1; o < 16; o <<= 1) {
            int t = __shfl_up(s, o, 64);
            if (lane >= o) s += t;
        }
        if (lane < 16) wsum[lane] = s;
    }
    __syncthreads();
    int woff = (wid > 0) ? wsum[wid - 1] : 0;
    if (idx < N) partial[idx] = woff + x - v;
    if (tid == 0) bsum[blockIdx.x] = wsum[15];
    __syncthreads();
    if (tid < 64 && hist[tid]) atomicAdd(&bcnt[tid], hist[tid]);
}

__global__ __launch_bounds__(256) void k_scanB(
    int* __restrict__ bsum, int nb, int* __restrict__ totalp)
{
    __shared__ int s[256];
    int tid = threadIdx.x;
    int v = (tid < nb) ? bsum[tid] : 0;
    s[tid] = v;
    __syncthreads();
#pragma unroll
    for (int off = 1; off < 256; off <<= 1) {
        int t = (tid >= off) ? s[tid - off] : 0;
        __syncthreads();
        s[tid] += t;
        __syncthreads();
    }
    if (tid < nb) bsum[tid] = s[tid] - v;
    if (tid == 0) totalp[0] = s[255];
}

__global__ __launch_bounds__(256) void k_scanC(
    int* __restrict__ offsets, const int* __restrict__ bsum,
    int* __restrict__ cursor, int N)
{
    int idx = blockIdx.x * 256 + threadIdx.x;
    if (idx >= N) return;
    int o = offsets[idx] + bsum[idx >> 10];
    offsets[idx] = o;
    cursor[idx] = o;
}

// entries[pos] = {src, eid, e.x, e.y}, grouped by dst
__global__ __launch_bounds__(256) void k_fill(
    const int* __restrict__ src, const int* __restrict__ dst,
    const float* __restrict__ ep, int* __restrict__ cursor,
    int4* __restrict__ entries, int E)
{
    int ei = blockIdx.x * 256 + threadIdx.x;
    if (ei >= E) return;
    int pos = atomicAdd(&cursor[dst[ei]], 1);
    float2 ev = *(const float2*)(ep + 2 * (size_t)ei);
    entries[pos] = make_int4(src[ei], ei, __float_as_int(ev.x), __float_as_int(ev.y));
}

__global__ __launch_bounds__(64) void k_bscan(
    int* __restrict__ bcnt, int* __restrict__ bcur)
{
    int lane = threadIdx.x;
    int v = bcnt[lane];
    int x = v;
#pragma unroll
    for (int o = 1; o < 64; o <<= 1) {
        int t = __shfl_up(x, o, 64);
        if (lane >= o) x += t;
    }
    bcur[lane] = x - v;   // exclusive
}

__global__ __launch_bounds__(256) void k_bfill(
    const int* __restrict__ offsets, int* __restrict__ bcur,
    int* __restrict__ perm, int N)
{
    __shared__ int hist[64];
    __shared__ int lbase[64];
    int tid = threadIdx.x;
    if (tid < 64) hist[tid] = 0;
    __syncthreads();
    int idx = blockIdx.x * 256 + tid;
    int b = 0, rank = 0;
    bool valid = (idx < N);
    if (valid) {
        int d = offsets[idx + 1] - offsets[idx];
        b = deg_bucket(d);
        rank = atomicAdd(&hist[b], 1);   // LDS: cheap
    }
    __syncthreads();
    if (tid < 64) lbase[tid] = hist[tid] ? atomicAdd(&bcur[tid], hist[tid]) : 0;
    __syncthreads();
    if (valid) perm[lbase[b] + rank] = idx;
}

// --------- epilogue matmuls: from x row (staged in xs) -> next-head tables ----
// WRITE==1: comb row {A|H} interleaved 16B chunks + B
// WRITE==2: compact A (128B/node) + B   (final head: no H needed)
template <int WRITE>
static __device__ __forceinline__ void epi_tables16(
    float (*xs)[68], int row, int li, int r, float4 o,
    const float* __restrict__ WAn, const float* __restrict__ bAn,
    const float* __restrict__ WBn,
    ushort_t* __restrict__ tab_out, ushort_t* __restrict__ B_out)
{
    xs[row][4*li+0] = o.x; xs[row][4*li+1] = o.y;
    xs[row][4*li+2] = o.z; xs[row][4*li+3] = o.w;
    float4 aA = *(const float4*)(bAn + 4 * li);
    float4 aB = make_float4(0.f, 0.f, 0.f, 0.f);
#pragma unroll
    for (int k = 0; k < 64; k++) {
        float xk = xs[row][k];
        float4 wa = *(const float4*)(WAn + k * 64 + 4 * li);
        float4 wb = *(const float4*)(WBn + k * 64 + 4 * li);
        aA.x += xk * wa.x; aA.y += xk * wa.y; aA.z += xk * wa.z; aA.w += xk * wa.w;
        aB.x += xk * wb.x; aB.y += xk * wb.y; aB.z += xk * wb.z; aB.w += xk * wb.w;
    }
    if (WRITE == 1) {
        int4 cw;
        cw.x = (int)pack2(aA.x, aA.y);
        cw.y = (int)pack2(aA.z, aA.w);
        cw.z = (int)pack2(o.x, o.y);
        cw.w = (int)pack2(o.z, o.w);
        *(int4*)(tab_out + (size_t)r * 128 + li * 8) = cw;
    } else {
        ushort4 oa;
        oa.x = f2bf(aA.x); oa.y = f2bf(aA.y); oa.z = f2bf(aA.z); oa.w = f2bf(aA.w);
        *(ushort4*)(tab_out + (size_t)r * 64 + 4 * li) = oa;
    }
    ushort4 ob;
    ob.x = f2bf(aB.x); ob.y = f2bf(aB.y); ob.z = f2bf(aB.z); ob.w = f2bf(aB.w);
    *(ushort4*)(B_out + (size_t)r * 64 + 4 * li) = ob;
}

// ---- GIN MLP + residual for one node row (x staged/overwritten in xs[row]) ----
template <int EPI>
static __device__ __forceinline__ void node_mlp(
    float (*xs)[68], int row, int li, int r, float4 acc, float epsv,
    const float* __restrict__ h, float* __restrict__ hout,
    const float* __restrict__ W1, const float* __restrict__ b1,
    const float* __restrict__ s1, const float* __restrict__ sh1,
    const float* __restrict__ W2, const float* __restrict__ b2,
    const float* __restrict__ as_, const float* __restrict__ ash,
    const float* __restrict__ gs, const float* __restrict__ gsh,
    const float* __restrict__ WAn, const float* __restrict__ bAn,
    const float* __restrict__ WBn,
    ushort_t* __restrict__ tab_out, ushort_t* __restrict__ B_out)
{
    float4 hv = *(const float4*)(h + (size_t)r * 64 + 4 * li);
    xs[row][4*li+0] = epsv * hv.x + acc.x;
    xs[row][4*li+1] = epsv * hv.y + acc.y;
    xs[row][4*li+2] = epsv * hv.z + acc.z;
    xs[row][4*li+3] = epsv * hv.w + acc.w;

    float4 t = *(const float4*)(b1 + 4 * li);
#pragma unroll
    for (int kk = 0; kk < 64; kk++) {
        float xk = xs[row][kk];
        float4 wv = *(const float4*)(W1 + kk * 64 + 4 * li);
        t.x += xk * wv.x; t.y += xk * wv.y; t.z += xk * wv.z; t.w += xk * wv.w;
    }
    {
        float4 sc = *(const float4*)(s1 + 4 * li);
        float4 sh = *(const float4*)(sh1 + 4 * li);
        t.x = fmaxf(t.x * sc.x + sh.x, 0.f);
        t.y = fmaxf(t.y * sc.y + sh.y, 0.f);
        t.z = fmaxf(t.z * sc.z + sh.z, 0.f);
        t.w = fmaxf(t.w * sc.w + sh.w, 0.f);
    }
    // overwrite x with t (all reads above precede these stores in-wave)
    xs[row][4*li+0] = t.x; xs[row][4*li+1] = t.y;
    xs[row][4*li+2] = t.z; xs[row][4*li+3] = t.w;

    float4 u = *(const float4*)(b2 + 4 * li);
#pragma unroll
    for (int kk = 0; kk < 64; kk++) {
        float tk = xs[row][kk];
        float4 wv = *(const float4*)(W2 + kk * 64 + 4 * li);
        u.x += tk * wv.x; u.y += tk * wv.y; u.z += tk * wv.z; u.w += tk * wv.w;
    }
    {
        float4 sc = *(const float4*)(as_ + 4 * li);
        float4 sh = *(const float4*)(ash + 4 * li);
        u.x = fmaxf(u.x * sc.x + sh.x, 0.f);
        u.y = fmaxf(u.y * sc.y + sh.y, 0.f);
        u.z = fmaxf(u.z * sc.z + sh.z, 0.f);
        u.w = fmaxf(u.w * sc.w + sh.w, 0.f);
        sc = *(const float4*)(gs + 4 * li);
        sh = *(const float4*)(gsh + 4 * li);
        u.x = fmaxf(u.x * sc.x + sh.x, 0.f);
        u.y = fmaxf(u.y * sc.y + sh.y, 0.f);
        u.z = fmaxf(u.z * sc.z + sh.z, 0.f);
        u.w = fmaxf(u.w * sc.w + sh.w, 0.f);
    }
    float4 o = make_float4(hv.x + u.x, hv.y + u.y, hv.z + u.z, hv.w + u.w);
    *(float4*)(hout + (size_t)r * 64 + 4 * li) = o;
    if (EPI == 1)
        epi_tables16<1>(xs, row, li, r, o, WAn, bAn, WBn, tab_out, B_out);
    else if (EPI == 2)
        epi_tables16<2>(xs, row, li, r, o, WAn, bAn, WBn, tab_out, B_out);
}

// ------------- embed: h0 = h_in @ W + b; then head-0 comb/B tables ---------
__global__ __launch_bounds__(256) void k_embed_ab(
    const float* __restrict__ in, const float* __restrict__ W,
    const float* __restrict__ bias, float* __restrict__ hout,
    const float* __restrict__ WA, const float* __restrict__ bA,
    const float* __restrict__ WB,
    ushort_t* __restrict__ comb_out, ushort_t* __restrict__ B_out, int N)
{
    __shared__ float xs[16][68];
    const int row16 = threadIdx.x >> 4;
    const int li    = threadIdx.x & 15;
    const int r     = blockIdx.x * 16 + row16;
    if (r >= N) return;
    float4 x4 = *(const float4*)(in + (size_t)r * 64 + 4 * li);
    xs[row16][4*li+0] = x4.x; xs[row16][4*li+1] = x4.y;
    xs[row16][4*li+2] = x4.z; xs[row16][4*li+3] = x4.w;
    float4 acc = *(const float4*)(bias + 4 * li);
#pragma unroll
    for (int k = 0; k < 64; k++) {
        float xk = xs[row16][k];
        float4 wv = *(const float4*)(W + k * 64 + 4 * li);
        acc.x += xk * wv.x; acc.y += xk * wv.y;
        acc.z += xk * wv.z; acc.w += xk * wv.w;
    }
    *(float4*)(hout + (size_t)r * 64 + 4 * li) = acc;
    epi_tables16<1>(xs, row16, li, r, acc, WA, bA, WB, comb_out, B_out);
}

// ------------- standalone tables (fallback when ws too small) -------------
__global__ __launch_bounds__(256) void k_tables(
    const float* __restrict__ h,
    const float* __restrict__ WA, const float* __restrict__ bA,
    const float* __restrict__ WB,
    ushort_t* __restrict__ comb_out, ushort_t* __restrict__ B_out, int N)
{
    __shared__ float xs[16][68];
    const int row16 = threadIdx.x >> 4;
    const int li    = threadIdx.x & 15;
    const int r     = blockIdx.x * 16 + row16;
    if (r >= N) return;
    float4 o = *(const float4*)(h + (size_t)r * 64 + 4 * li);
    epi_tables16<1>(xs, row16, li, r, o, WA, bA, WB, comb_out, B_out);
}

// per-edge helper macros for k_fused (use locals: li, wc0, wc1, w2v, bb2, score_csr, MODE)
#define GATH(s) (*(const int4*)(comb + (size_t)(s) * 128 + li * 8))
#define AGGC(acc, c) { acc.x += bf2f_lo((uint_t)(c).z); acc.y += bf2f_hi((uint_t)(c).z); \
                       acc.z += bf2f_lo((uint_t)(c).w); acc.w += bf2f_hi((uint_t)(c).w); }
#define SCOR(kk, e_, c_, brow_) { \
    float p_ = edge_p2((uint_t)(c_).x, (uint_t)(c_).y, brow_, \
                       __int_as_float((e_).z), __int_as_float((e_).w), wc0, wc1, w2v); \
    RED16(p_) \
    if (li == 0) { if (MODE == 0) score_csr[kk] = p_ + bb2; else score_csr[kk] += p_ + bb2; } }

// ------------- fused layer: head i score + GIN layer i + next-head tables -----
// TWO nodes per 16-lane group (perm-adjacent -> similar degree). Dual-quad main
// loop keeps 8 independent comb gathers in flight; per-node drain 4-wide + tail.
// MODE 0: score_csr = ; 1: score_csr +=    EPI: 0 none, 1 comb+B, 2 compactA+B
template <int MODE, int EPI>
__global__ __launch_bounds__(256) void k_fused(
    const float* __restrict__ h, float* __restrict__ hout,
    const ushort_t* __restrict__ comb, const ushort_t* __restrict__ Bm,
    const int4* __restrict__ entries, const int* __restrict__ offsets,
    const int* __restrict__ perm,
    float* __restrict__ score_csr,
    const float* __restrict__ Wc, const float* __restrict__ W2v,
    const float* __restrict__ b2p, const float* __restrict__ epsp,
    const float* __restrict__ W1, const float* __restrict__ b1,
    const float* __restrict__ s1, const float* __restrict__ sh1,
    const float* __restrict__ W2, const float* __restrict__ b2,
    const float* __restrict__ as_, const float* __restrict__ ash,
    const float* __restrict__ gs, const float* __restrict__ gsh,
    const float* __restrict__ WAn, const float* __restrict__ bAn,
    const float* __restrict__ WBn,
    ushort_t* __restrict__ tab_out, ushort_t* __restrict__ B_out, int N)
{
    __shared__ float xs[32][68];
    const int gq = threadIdx.x >> 4;       // 0..15
    const int li = threadIdx.x & 15;
    const int i0 = blockIdx.x * 32 + 2 * gq;
    const int i1 = i0 + 1;
    if (i0 >= N) return;
    const int r0 = perm[i0];
    const bool v1 = (i1 < N);
    const int r1 = v1 ? perm[i1] : r0;

    const float4 wc0 = *(const float4*)(Wc + li*4);
    const float4 wc1 = *(const float4*)(Wc + 64 + li*4);
    const float4 w2v = *(const float4*)(W2v + li*4);
    const float bb2 = b2p[0];
    ushort4 bu0 = *(const ushort4*)(Bm + (size_t)r0 * 64 + li*4);
    ushort4 bu1 = *(const ushort4*)(Bm + (size_t)r1 * 64 + li*4);
    const float4 brow0 = make_float4(bf2f(bu0.x), bf2f(bu0.y), bf2f(bu0.z), bf2f(bu0.w));
    const float4 brow1 = make_float4(bf2f(bu1.x), bf2f(bu1.y), bf2f(bu1.z), bf2f(bu1.w));

    const int end0 = offsets[r0 + 1];
    int k0 = offsets[r0];
    int k1 = 0, end1 = 0;
    if (v1) { k1 = offsets[r1]; end1 = offsets[r1 + 1]; }
    float4 acc0 = make_float4(0.f, 0.f, 0.f, 0.f);
    float4 acc1 = make_float4(0.f, 0.f, 0.f, 0.f);

    // dual-quad: 8 independent gathers (4 per node) in flight
    while (k0 + 3 < end0 && k1 + 3 < end1) {
        int4 a0 = entries[k0], a1 = entries[k0+1], a2 = entries[k0+2], a3 = entries[k0+3];
        int4 f0 = entries[k1], f1 = entries[k1+1], f2 = entries[k1+2], f3 = entries[k1+3];
        int4 ca0 = GATH(a0.x), ca1 = GATH(a1.x), ca2 = GATH(a2.x), ca3 = GATH(a3.x);
        int4 cb0 = GATH(f0.x), cb1 = GATH(f1.x), cb2 = GATH(f2.x), cb3 = GATH(f3.x);
        AGGC(acc0, ca0) AGGC(acc0, ca1) AGGC(acc0, ca2) AGGC(acc0, ca3)
        AGGC(acc1, cb0) AGGC(acc1, cb1) AGGC(acc1, cb2) AGGC(acc1, cb3)
        SCOR(k0, a0, ca0, brow0) SCOR(k0+1, a1, ca1, brow0)
        SCOR(k0+2, a2, ca2, brow0) SCOR(k0+3, a3, ca3, brow0)
        SCOR(k1, f0, cb0, brow1) SCOR(k1+1, f1, cb1, brow1)
        SCOR(k1+2, f2, cb2, brow1) SCOR(k1+3, f3, cb3, brow1)
        k0 += 4; k1 += 4;
    }
    // drain node0
    for (; k0 + 3 < end0; k0 += 4) {
        int4 a0 = entries[k0], a1 = entries[k0+1], a2 = entries[k0+2], a3 = entries[k0+3];
        int4 ca0 = GATH(a0.x), ca1 = GATH(a1.x), ca2 = GATH(a2.x), ca3 = GATH(a3.x);
        AGGC(acc0, ca0) AGGC(acc0, ca1) AGGC(acc0, ca2) AGGC(acc0, ca3)
        SCOR(k0, a0, ca0, brow0) SCOR(k0+1, a1, ca1, brow0)
        SCOR(k0+2, a2, ca2, brow0) SCOR(k0+3, a3, ca3, brow0)
    }
    for (; k0 < end0; k0++) {
        int4 a0 = entries[k0];
        int4 ca0 = GATH(a0.x);
        AGGC(acc0, ca0)
        SCOR(k0, a0, ca0, brow0)
    }
    // drain node1
    for (; k1 + 3 < end1; k1 += 4) {
        int4 f0 = entries[k1], f1 = entries[k1+1], f2 = entries[k1+2], f3 = entries[k1+3];
        int4 cb0 = GATH(f0.x), cb1 = GATH(f1.x), cb2 = GATH(f2.x), cb3 = GATH(f3.x);
        AGGC(acc1, cb0) AGGC(acc1, cb1) AGGC(acc1, cb2) AGGC(acc1, cb3)
        SCOR(k1, f0, cb0, brow1) SCOR(k1+1, f1, cb1, brow1)
        SCOR(k1+2, f2, cb2, brow1) SCOR(k1+3, f3, cb3, brow1)
    }
    for (; k1 < end1; k1++) {
        int4 f0 = entries[k1];
        int4 cb0 = GATH(f0.x);
        AGGC(acc1, cb0)
        SCOR(k1, f0, cb0, brow1)
    }

    const float epsv = 1.0f + epsp[0];
    node_mlp<EPI>(xs, 2*gq, li, r0, acc0, epsv, h, hout,
                  W1, b1, s1, sh1, W2, b2, as_, ash, gs, gsh,
                  WAn, bAn, WBn, tab_out, B_out);
    if (v1)
        node_mlp<EPI>(xs, 2*gq+1, li, r1, acc1, epsv, h, hout,
                      W1, b1, s1, sh1, W2, b2, as_, ash, gs, gsh,
                      WAn, bAn, WBn, tab_out, B_out);
}

// ------------- final head: score_out[eid] = relu(score_csr + pred) -----------
// COMPACT: A from compact 128B/node table; else A-half of comb (int2 strided).
template <int COMPACT>
__global__ __launch_bounds__(256) void k_head(
    const ushort_t* __restrict__ Atab,
    const ushort_t* __restrict__ Bm,
    const int4* __restrict__ entries, const int* __restrict__ offsets,
    const int* __restrict__ perm,
    const float* __restrict__ score_csr, float* __restrict__ score_out,
    const float* __restrict__ Wc, const float* __restrict__ W2v,
    const float* __restrict__ b2p, int N)
{
    const int row16 = threadIdx.x >> 4;
    const int li    = threadIdx.x & 15;
    const int idx   = blockIdx.x * 16 + row16;
    if (idx >= N) return;
    const int r = perm[idx];

    const float4 wc0 = *(const float4*)(Wc + li*4);
    const float4 wc1 = *(const float4*)(Wc + 64 + li*4);
    const float4 w2v = *(const float4*)(W2v + li*4);
    const float bb2 = b2p[0];
    ushort4 bu = *(const ushort4*)(Bm + (size_t)r * 64 + li*4);
    const float4 brow = make_float4(bf2f(bu.x), bf2f(bu.y), bf2f(bu.z), bf2f(bu.w));

    const int beg = offsets[r], end = offsets[r + 1];

#define ALOAD(s, ax, ay) { \
    if (COMPACT) { \
        ushort4 a_ = *(const ushort4*)(Atab + (size_t)(s) * 64 + li * 4); \
        ax = (uint_t)a_.x | ((uint_t)a_.y << 16); \
        ay = (uint_t)a_.z | ((uint_t)a_.w << 16); \
    } else { \
        int2 d_ = *(const int2*)(Atab + (size_t)(s) * 128 + li * 8); \
        ax = (uint_t)d_.x; ay = (uint_t)d_.y; \
    } }
#define HSCOR(kk, e_, ax, ay) { \
    float p_ = edge_p2(ax, ay, brow, __int_as_float((e_).z), __int_as_float((e_).w), \
                       wc0, wc1, w2v); \
    RED16(p_) \
    if (li == 0) score_out[(e_).y] = fmaxf(score_csr[kk] + p_ + bb2, 0.f); }

    int k = beg;
    for (; k + 3 < end; k += 4) {
        int4 e0 = entries[k], e1 = entries[k+1], e2 = entries[k+2], e3 = entries[k+3];
        uint_t ax0, ay0, ax1, ay1, ax2, ay2, ax3, ay3;
        ALOAD(e0.x, ax0, ay0) ALOAD(e1.x, ax1, ay1)
        ALOAD(e2.x, ax2, ay2) ALOAD(e3.x, ax3, ay3)
        HSCOR(k, e0, ax0, ay0) HSCOR(k+1, e1, ax1, ay1)
        HSCOR(k+2, e2, ax2, ay2) HSCOR(k+3, e3, ax3, ay3)
    }
    for (; k < end; k++) {
        int4 e0 = entries[k];
        uint_t ax0, ay0;
        ALOAD(e0.x, ax0, ay0)
        HSCOR(k, e0, ax0, ay0)
    }
#undef ALOAD
#undef HSCOR
}

extern "C" void kernel_launch(void* const* d_in, const int* in_sizes, int n_in,
                              void* d_out, int out_size, void* d_ws, size_t ws_size,
                              hipStream_t stream) {
    const float* h_in  = (const float*)d_in[0];
    const float* e     = (const float*)d_in[1];
    const int*   src   = (const int*)d_in[2];
    const int*   dst   = (const int*)d_in[3];
    const float* emb_W = (const float*)d_in[4];
    const float* emb_b = (const float*)d_in[5];
    const float* eps   = (const float*)d_in[6];
    const float* mW1   = (const float*)d_in[7];
    const float* mb1   = (const float*)d_in[8];
    const float* mbs   = (const float*)d_in[9];
    const float* mbsh  = (const float*)d_in[10];
    const float* mW2   = (const float*)d_in[11];
    const float* mb2   = (const float*)d_in[12];
    const float* as_   = (const float*)d_in[13];
    const float* ash   = (const float*)d_in[14];
    const float* gs    = (const float*)d_in[15];
    const float* gsh   = (const float*)d_in[16];
    const float* pW1   = (const float*)d_in[17];
    const float* pb1   = (const float*)d_in[18];
    const float* pW2   = (const float*)d_in[19];
    const float* pb2   = (const float*)d_in[20];

    const int N  = in_sizes[0] / 64;
    const int E  = in_sizes[2];
    const int Lr = in_sizes[6];
    const size_t nrow = (size_t)N * 64;

    float* score = (float*)d_out;

    char* wp = (char*)d_ws;
    auto take = [&](size_t b) -> char* {
        char* p = wp; wp += (b + 255) & ~(size_t)255; return p;
    };
    float*    h0        = (float*)take(nrow * 4);
    float*    h1        = (float*)take(nrow * 4);
    ushort_t* comb0     = (ushort_t*)take(nrow * 4);   // [N][128] ushort
    ushort_t* B0        = (ushort_t*)take(nrow * 2);
    int4*     entries   = (int4*)take((size_t)E * 16);
    float*    score_csr = (float*)take((size_t)E * 4);
    int*      offsets   = (int*)take((size_t)(N + 1) * 4);
    int*      cursor    = (int*)take((size_t)N * 4);
    int*      bsum      = (int*)take(1024);
    int*      perm      = (int*)take((size_t)N * 4);
    int*      bcnt      = (int*)take(64 * 4);
    int*      bcur      = (int*)take(64 * 4);
    ushort_t* comb1     = (ushort_t*)take(nrow * 4);
    ushort_t* B1        = (ushort_t*)take(nrow * 2);
    ushort_t* Afin      = (ushort_t*)take(nrow * 2);
    size_t need_epi = (size_t)(wp - (char*)d_ws);

    const bool use_epi = ws_size >= need_epi;

    const int rowBlocks  = (N + 15) / 16;
    const int dualBlocks = (N + 31) / 32;
    const int edgeGrid   = (E + 255) / 256;
    const int nb         = (N + 1023) / 1024;

    // ---- CSR build + degree histogram ----
    hipMemsetAsync(cursor, 0, (size_t)N * sizeof(int), stream);
    hipMemsetAsync(bcnt, 0, 64 * sizeof(int), stream);
    k_count<<<edgeGrid, 256, 0, stream>>>(dst, cursor, E);
    k_scanA<<<nb, 1024, 0, stream>>>(cursor, offsets, bsum, bcnt, N);
    k_scanB<<<1, 256, 0, stream>>>(bsum, nb, offsets + N);
    k_scanC<<<(N + 255) / 256, 256, 0, stream>>>(offsets, bsum, cursor, N);
    k_fill<<<edgeGrid, 256, 0, stream>>>(src, dst, e, cursor, entries, E);

    // ---- degree-bucket permutation (descending) ----
    k_bscan<<<1, 64, 0, stream>>>(bcnt, bcur);
    k_bfill<<<(N + 255) / 256, 256, 0, stream>>>(offsets, bcur, perm, N);

    // ---- embed + head-0 tables ----
    k_embed_ab<<<rowBlocks, 256, 0, stream>>>(
        h_in, emb_W, emb_b, h0, pW1, pb1, pW1 + 64 * 64, comb0, B0, N);

    float* hcur = h0;       float* hnext = h1;
    ushort_t* Ccur = comb0; ushort_t* Cnxt = use_epi ? comb1 : comb0;
    ushort_t* Bcur = B0;    ushort_t* Bnxt = use_epi ? B1 : B0;

    for (int i = 0; i < Lr; i++) {
        const float* pw  = pW1 + (size_t)i * 130 * 64;
        const float* Wc  = pw + 128 * 64;
        const float* w2  = pW2 + (size_t)i * 64;
        const float* b2  = pb2 + i;
        const float* pwn = pW1 + (size_t)(i + 1) * 130 * 64;
        const float* gW1 = mW1 + (size_t)i * 64 * 64;
        const float* gW2 = mW2 + (size_t)i * 64 * 64;
        const bool last = (i == Lr - 1);

        if (use_epi) {
            ushort_t* tout = last ? Afin : Cnxt;
            if (i == 0 && !last)
                k_fused<0,1><<<dualBlocks, 256, 0, stream>>>(
                    hcur, hnext, Ccur, Bcur, entries, offsets, perm, score_csr,
                    Wc, w2, b2, eps + i,
                    gW1, mb1 + i*64, mbs + i*64, mbsh + i*64, gW2, mb2 + i*64,
                    as_ + i*64, ash + i*64, gs + i*64, gsh + i*64,
                    pwn, pb1 + (i+1)*64, pwn + 64*64, tout, Bnxt, N);
            else if (i == 0 && last)
                k_fused<0,2><<<dualBlocks, 256, 0, stream>>>(
                    hcur, hnext, Ccur, Bcur, entries, offsets, perm, score_csr,
                    Wc, w2, b2, eps + i,
                    gW1, mb1 + i*64, mbs + i*64, mbsh + i*64, gW2, mb2 + i*64,
                    as_ + i*64, ash + i*64, gs + i*64, gsh + i*64,
                    pwn, pb1 + (i+1)*64, pwn + 64*64, tout, Bnxt, N);
            else if (!last)
                k_fused<1,1><<<dualBlocks, 256, 0, stream>>>(
                    hcur, hnext, Ccur, Bcur, entries, offsets, perm, score_csr,
                    Wc, w2, b2, eps + i,
                    gW1, mb1 + i*64, mbs + i*64, mbsh + i*64, gW2, mb2 + i*64,
                    as_ + i*64, ash + i*64, gs + i*64, gsh + i*64,
                    pwn, pb1 + (i+1)*64, pwn + 64*64, tout, Bnxt, N);
            else
                k_fused<1,2><<<dualBlocks, 256, 0, stream>>>(
                    hcur, hnext, Ccur, Bcur, entries, offsets, perm, score_csr,
                    Wc, w2, b2, eps + i,
                    gW1, mb1 + i*64, mbs + i*64, mbsh + i*64, gW2, mb2 + i*64,
                    as_ + i*64, ash + i*64, gs + i*64, gsh + i*64,
                    pwn, pb1 + (i+1)*64, pwn + 64*64, tout, Bnxt, N);
            { ushort_t* t = Ccur; Ccur = Cnxt; Cnxt = t; }
            { ushort_t* t = Bcur; Bcur = Bnxt; Bnxt = t; }
        } else {
            if (i == 0)
                k_fused<0,0><<<dualBlocks, 256, 0, stream>>>(
                    hcur, hnext, Ccur, Bcur, entries, offsets, perm, score_csr,
                    Wc, w2, b2, eps + i,
                    gW1, mb1 + i*64, mbs + i*64, mbsh + i*64, gW2, mb2 + i*64,
                    as_ + i*64, ash + i*64, gs + i*64, gsh + i*64,
                    nullptr, nullptr, nullptr, nullptr, nullptr, N);
            else
                k_fused<1,0><<<dualBlocks, 256, 0, stream>>>(
                    hcur, hnext, Ccur, Bcur, entries, offsets, perm, score_csr,
                    Wc, w2, b2, eps + i,
                    gW1, mb1 + i*64, mbs + i*64, mbsh + i*64, gW2, mb2 + i*64,
                    as_ + i*64, ash + i*64, gs + i*64, gsh + i*64,
                    nullptr, nullptr, nullptr, nullptr, nullptr, N);
            k_tables<<<rowBlocks, 256, 0, stream>>>(
                hnext, pwn, pb1 + (i+1)*64, pwn + 64*64, Ccur, Bcur, N);
        }
        { float* t = hcur; hcur = hnext; hnext = t; }
    }

    // ---- final head ----
    {
        const float* pw = pW1 + (size_t)Lr * 130 * 64;
        const float* Wc = pw + 128 * 64;
        const float* w2 = pW2 + (size_t)Lr * 64;
        const float* b2 = pb2 + Lr;
        if (use_epi)
            k_head<1><<<rowBlocks, 256, 0, stream>>>(
                Afin, Bcur, entries, offsets, perm, score_csr, score,
                Wc, w2, b2, N);
        else
            k_head<0><<<rowBlocks, 256, 0, stream>>>(
                Ccur, Bcur, entries, offsets, perm, score_csr, score,
                Wc, w2, b2, N);
    }
}

// Round 11
// 587.779 us; speedup vs baseline: 2.4357x; 2.4357x over previous
//
#include <hip/hip_runtime.h>

typedef unsigned short ushort_t;
typedef unsigned int uint_t;

static __device__ __forceinline__ ushort_t f2bf(float f) {
    uint_t u = __float_as_uint(f);
    uint_t r = (u + 0x7FFFu + ((u >> 16) & 1u)) >> 16;   // RNE
    return (ushort_t)r;
}
static __device__ __forceinline__ float bf2f(ushort_t u) {
    return __uint_as_float(((uint_t)u) << 16);
}
static __device__ __forceinline__ float bf2f_lo(uint_t u) {
    return __uint_as_float(u << 16);
}
static __device__ __forceinline__ float bf2f_hi(uint_t u) {
    return __uint_as_float(u & 0xffff0000u);
}
static __device__ __forceinline__ uint_t pack2(float lo, float hi) {
    return (uint_t)f2bf(lo) | ((uint_t)f2bf(hi) << 16);
}

// score contribution of one edge: relu(A + B + e@Wc) . w2  (4 features/lane)
static __device__ __forceinline__ float edge_p2(
    uint_t ax, uint_t ay, float4 brow, float ex, float ey,
    float4 wc0, float4 wc1, float4 w2v)
{
    float z0 = bf2f_lo(ax) + brow.x + ex*wc0.x + ey*wc1.x; z0 = fmaxf(z0, 0.f);
    float z1 = bf2f_hi(ax) + brow.y + ex*wc0.y + ey*wc1.y; z1 = fmaxf(z1, 0.f);
    float z2 = bf2f_lo(ay) + brow.z + ex*wc0.z + ey*wc1.z; z2 = fmaxf(z2, 0.f);
    float z3 = bf2f_hi(ay) + brow.w + ex*wc0.w + ey*wc1.w; z3 = fmaxf(z3, 0.f);
    return z0*w2v.x + z1*w2v.y + z2*w2v.z + z3*w2v.w;
}

#define RED16(p) { p += __shfl_xor(p,1); p += __shfl_xor(p,2); \
                   p += __shfl_xor(p,4); p += __shfl_xor(p,8); }

// ---------------- CSR build ----------------
__global__ __launch_bounds__(256) void k_count(
    const int* __restrict__ dst, int* __restrict__ deg, int E)
{
    int e = blockIdx.x * 256 + threadIdx.x;
    if (e < E) atomicAdd(&deg[dst[e]], 1);
}

static __device__ __forceinline__ int deg_bucket(int d) {
    return d >= 63 ? 0 : (63 - d);
}

// per-block (1024) exclusive scan + degree-bucket histogram (fused)
__global__ __launch_bounds__(1024) void k_scanA(
    const int* __restrict__ deg, int* __restrict__ partial,
    int* __restrict__ bsum, int* __restrict__ bcnt, int N)
{
    __shared__ int wsum[16];
    __shared__ int hist[64];
    int tid = threadIdx.x, lane = tid & 63, wid = tid >> 6;
    if (tid < 64) hist[tid] = 0;
    __syncthreads();
    int idx = blockIdx.x * 1024 + tid;
    int v = (idx < N) ? deg[idx] : 0;
    if (idx < N) atomicAdd(&hist[deg_bucket(v)], 1);
    int x = v;
#pragma unroll
    for (int o = 1; o < 64; o <<= 1) {
        int t = __shfl_up(x, o, 64);
        if (lane >= o) x += t;
    }
    if (lane == 63) wsum[wid] = x;
    __syncthreads();
    if (wid == 0) {
        int s = (lane < 16) ? wsum[lane] : 0;
#pragma unroll
        for (int o = 1; o < 16; o <<= 1) {
            int t = __shfl_up(s, o, 64);
            if (lane >= o) s += t;
        }
        if (lane < 16) wsum[lane] = s;
    }
    __syncthreads();
    int woff = (wid > 0) ? wsum[wid - 1] : 0;
    if (idx < N) partial[idx] = woff + x - v;
    if (tid == 0) bsum[blockIdx.x] = wsum[15];
    __syncthreads();
    if (tid < 64 && hist[tid]) atomicAdd(&bcnt[tid], hist[tid]);
}

__global__ __launch_bounds__(256) void k_scanB(
    int* __restrict__ bsum, int nb, int* __restrict__ totalp)
{
    __shared__ int s[256];
    int tid = threadIdx.x;
    int v = (tid < nb) ? bsum[tid] : 0;
    s[tid] = v;
    __syncthreads();
#pragma unroll
    for (int off = 1; off < 256; off <<= 1) {
        int t = (tid >= off) ? s[tid - off] : 0;
        __syncthreads();
        s[tid] += t;
        __syncthreads();
    }
    if (tid < nb) bsum[tid] = s[tid] - v;
    if (tid == 0) totalp[0] = s[255];
}

__global__ __launch_bounds__(256) void k_scanC(
    int* __restrict__ offsets, const int* __restrict__ bsum,
    int* __restrict__ cursor, int N)
{
    int idx = blockIdx.x * 256 + threadIdx.x;
    if (idx >= N) return;
    int o = offsets[idx] + bsum[idx >> 10];
    offsets[idx] = o;
    cursor[idx] = o;
}

// entries[pos] = {src, eid, e.x, e.y}, grouped by dst
__global__ __launch_bounds__(256) void k_fill(
    const int* __restrict__ src, const int* __restrict__ dst,
    const float* __restrict__ ep, int* __restrict__ cursor,
    int4* __restrict__ entries, int E)
{
    int ei = blockIdx.x * 256 + threadIdx.x;
    if (ei >= E) return;
    int pos = atomicAdd(&cursor[dst[ei]], 1);
    float2 ev = *(const float2*)(ep + 2 * (size_t)ei);
    entries[pos] = make_int4(src[ei], ei, __float_as_int(ev.x), __float_as_int(ev.y));
}

__global__ __launch_bounds__(64) void k_bscan(
    int* __restrict__ bcnt, int* __restrict__ bcur)
{
    int lane = threadIdx.x;
    int v = bcnt[lane];
    int x = v;
#pragma unroll
    for (int o = 1; o < 64; o <<= 1) {
        int t = __shfl_up(x, o, 64);
        if (lane >= o) x += t;
    }
    bcur[lane] = x - v;   // exclusive
}

__global__ __launch_bounds__(256) void k_bfill(
    const int* __restrict__ offsets, int* __restrict__ bcur,
    int* __restrict__ perm, int N)
{
    __shared__ int hist[64];
    __shared__ int lbase[64];
    int tid = threadIdx.x;
    if (tid < 64) hist[tid] = 0;
    __syncthreads();
    int idx = blockIdx.x * 256 + tid;
    int b = 0, rank = 0;
    bool valid = (idx < N);
    if (valid) {
        int d = offsets[idx + 1] - offsets[idx];
        b = deg_bucket(d);
        rank = atomicAdd(&hist[b], 1);   // LDS: cheap
    }
    __syncthreads();
    if (tid < 64) lbase[tid] = hist[tid] ? atomicAdd(&bcur[tid], hist[tid]) : 0;
    __syncthreads();
    if (valid) perm[lbase[b] + rank] = idx;
}

// --------- epilogue matmuls: from x row (staged in xs) -> next-head tables ----
// WRITE==1: comb row {A|H} interleaved 16B chunks + B
// WRITE==2: compact A (128B/node) + B   (final head: no H needed)
template <int WRITE>
static __device__ __forceinline__ void epi_tables16(
    float (*xs)[68], int row, int li, int r, float4 o,
    const float* __restrict__ WAn, const float* __restrict__ bAn,
    const float* __restrict__ WBn,
    ushort_t* __restrict__ tab_out, ushort_t* __restrict__ B_out)
{
    xs[row][4*li+0] = o.x; xs[row][4*li+1] = o.y;
    xs[row][4*li+2] = o.z; xs[row][4*li+3] = o.w;
    float4 aA = *(const float4*)(bAn + 4 * li);
    float4 aB = make_float4(0.f, 0.f, 0.f, 0.f);
#pragma unroll
    for (int k = 0; k < 64; k++) {
        float xk = xs[row][k];
        float4 wa = *(const float4*)(WAn + k * 64 + 4 * li);
        float4 wb = *(const float4*)(WBn + k * 64 + 4 * li);
        aA.x += xk * wa.x; aA.y += xk * wa.y; aA.z += xk * wa.z; aA.w += xk * wa.w;
        aB.x += xk * wb.x; aB.y += xk * wb.y; aB.z += xk * wb.z; aB.w += xk * wb.w;
    }
    if (WRITE == 1) {
        int4 cw;
        cw.x = (int)pack2(aA.x, aA.y);
        cw.y = (int)pack2(aA.z, aA.w);
        cw.z = (int)pack2(o.x, o.y);
        cw.w = (int)pack2(o.z, o.w);
        *(int4*)(tab_out + (size_t)r * 128 + li * 8) = cw;
    } else {
        ushort4 oa;
        oa.x = f2bf(aA.x); oa.y = f2bf(aA.y); oa.z = f2bf(aA.z); oa.w = f2bf(aA.w);
        *(ushort4*)(tab_out + (size_t)r * 64 + 4 * li) = oa;
    }
    ushort4 ob;
    ob.x = f2bf(aB.x); ob.y = f2bf(aB.y); ob.z = f2bf(aB.z); ob.w = f2bf(aB.w);
    *(ushort4*)(B_out + (size_t)r * 64 + 4 * li) = ob;
}

// ------------- embed: h0 = h_in @ W + b; then head-0 comb/B tables ---------
__global__ __launch_bounds__(256) void k_embed_ab(
    const float* __restrict__ in, const float* __restrict__ W,
    const float* __restrict__ bias, float* __restrict__ hout,
    const float* __restrict__ WA, const float* __restrict__ bA,
    const float* __restrict__ WB,
    ushort_t* __restrict__ comb_out, ushort_t* __restrict__ B_out, int N)
{
    __shared__ float xs[16][68];
    const int row16 = threadIdx.x >> 4;
    const int li    = threadIdx.x & 15;
    const int r     = blockIdx.x * 16 + row16;
    if (r >= N) return;
    float4 x4 = *(const float4*)(in + (size_t)r * 64 + 4 * li);
    xs[row16][4*li+0] = x4.x; xs[row16][4*li+1] = x4.y;
    xs[row16][4*li+2] = x4.z; xs[row16][4*li+3] = x4.w;
    float4 acc = *(const float4*)(bias + 4 * li);
#pragma unroll
    for (int k = 0; k < 64; k++) {
        float xk = xs[row16][k];
        float4 wv = *(const float4*)(W + k * 64 + 4 * li);
        acc.x += xk * wv.x; acc.y += xk * wv.y;
        acc.z += xk * wv.z; acc.w += xk * wv.w;
    }
    *(float4*)(hout + (size_t)r * 64 + 4 * li) = acc;
    epi_tables16<1>(xs, row16, li, r, acc, WA, bA, WB, comb_out, B_out);
}

// ------------- standalone tables (fallback when ws too small) -------------
__global__ __launch_bounds__(256) void k_tables(
    const float* __restrict__ h,
    const float* __restrict__ WA, const float* __restrict__ bA,
    const float* __restrict__ WB,
    ushort_t* __restrict__ comb_out, ushort_t* __restrict__ B_out, int N)
{
    __shared__ float xs[16][68];
    const int row16 = threadIdx.x >> 4;
    const int li    = threadIdx.x & 15;
    const int r     = blockIdx.x * 16 + row16;
    if (r >= N) return;
    float4 o = *(const float4*)(h + (size_t)r * 64 + 4 * li);
    epi_tables16<1>(xs, row16, li, r, o, WA, bA, WB, comb_out, B_out);
}

// ------------- fused layer: head i score + GIN layer i + next-head tables -----
// 16 lanes per node, perm order; R8-proven 4-wide + tail edge loop.
// One combined {A|H} 16B gather per edge. Single LDS buffer MLP.
// MODE 0: score_csr = ; 1: score_csr +=    EPI: 0 none, 1 comb+B, 2 compactA+B
template <int MODE, int EPI>
__global__ __launch_bounds__(256) void k_fused(
    const float* __restrict__ h, float* __restrict__ hout,
    const ushort_t* __restrict__ comb, const ushort_t* __restrict__ Bm,
    const int4* __restrict__ entries, const int* __restrict__ offsets,
    const int* __restrict__ perm,
    float* __restrict__ score_csr,
    const float* __restrict__ Wc, const float* __restrict__ W2v,
    const float* __restrict__ b2p, const float* __restrict__ epsp,
    const float* __restrict__ W1, const float* __restrict__ b1,
    const float* __restrict__ s1, const float* __restrict__ sh1,
    const float* __restrict__ W2, const float* __restrict__ b2,
    const float* __restrict__ as_, const float* __restrict__ ash,
    const float* __restrict__ gs, const float* __restrict__ gsh,
    const float* __restrict__ WAn, const float* __restrict__ bAn,
    const float* __restrict__ WBn,
    ushort_t* __restrict__ tab_out, ushort_t* __restrict__ B_out, int N)
{
    __shared__ float xs[16][68];
    const int row16 = threadIdx.x >> 4;
    const int li    = threadIdx.x & 15;
    const int idx   = blockIdx.x * 16 + row16;
    if (idx >= N) return;
    const int r = perm[idx];

    const float4 wc0 = *(const float4*)(Wc + li*4);
    const float4 wc1 = *(const float4*)(Wc + 64 + li*4);
    const float4 w2v = *(const float4*)(W2v + li*4);
    const float bb2 = b2p[0];
    ushort4 bu = *(const ushort4*)(Bm + (size_t)r * 64 + li*4);
    const float4 brow = make_float4(bf2f(bu.x), bf2f(bu.y), bf2f(bu.z), bf2f(bu.w));

    const int beg = offsets[r], end = offsets[r + 1];
    float4 acc = make_float4(0.f, 0.f, 0.f, 0.f);

    int k = beg;
    for (; k + 3 < end; k += 4) {
        int4 e0 = entries[k], e1 = entries[k+1], e2 = entries[k+2], e3 = entries[k+3];
        int4 c0 = *(const int4*)(comb + (size_t)e0.x * 128 + li * 8);
        int4 c1 = *(const int4*)(comb + (size_t)e1.x * 128 + li * 8);
        int4 c2 = *(const int4*)(comb + (size_t)e2.x * 128 + li * 8);
        int4 c3 = *(const int4*)(comb + (size_t)e3.x * 128 + li * 8);
        acc.x += bf2f_lo(c0.z) + bf2f_lo(c1.z) + bf2f_lo(c2.z) + bf2f_lo(c3.z);
        acc.y += bf2f_hi(c0.z) + bf2f_hi(c1.z) + bf2f_hi(c2.z) + bf2f_hi(c3.z);
        acc.z += bf2f_lo(c0.w) + bf2f_lo(c1.w) + bf2f_lo(c2.w) + bf2f_lo(c3.w);
        acc.w += bf2f_hi(c0.w) + bf2f_hi(c1.w) + bf2f_hi(c2.w) + bf2f_hi(c3.w);
        float p0 = edge_p2((uint_t)c0.x, (uint_t)c0.y, brow,
                           __int_as_float(e0.z), __int_as_float(e0.w), wc0, wc1, w2v);
        float p1 = edge_p2((uint_t)c1.x, (uint_t)c1.y, brow,
                           __int_as_float(e1.z), __int_as_float(e1.w), wc0, wc1, w2v);
        float p2 = edge_p2((uint_t)c2.x, (uint_t)c2.y, brow,
                           __int_as_float(e2.z), __int_as_float(e2.w), wc0, wc1, w2v);
        float p3 = edge_p2((uint_t)c3.x, (uint_t)c3.y, brow,
                           __int_as_float(e3.z), __int_as_float(e3.w), wc0, wc1, w2v);
        RED16(p0) RED16(p1) RED16(p2) RED16(p3)
        if (li == 0) {
            if (MODE == 0) {
                score_csr[k]   = p0 + bb2; score_csr[k+1] = p1 + bb2;
                score_csr[k+2] = p2 + bb2; score_csr[k+3] = p3 + bb2;
            } else {
                score_csr[k]   += p0 + bb2; score_csr[k+1] += p1 + bb2;
                score_csr[k+2] += p2 + bb2; score_csr[k+3] += p3 + bb2;
            }
        }
    }
    for (; k < end; k++) {
        int4 e0 = entries[k];
        int4 c0 = *(const int4*)(comb + (size_t)e0.x * 128 + li * 8);
        acc.x += bf2f_lo((uint_t)c0.z); acc.y += bf2f_hi((uint_t)c0.z);
        acc.z += bf2f_lo((uint_t)c0.w); acc.w += bf2f_hi((uint_t)c0.w);
        float p0 = edge_p2((uint_t)c0.x, (uint_t)c0.y, brow,
                           __int_as_float(e0.z), __int_as_float(e0.w), wc0, wc1, w2v);
        RED16(p0)
        if (li == 0) {
            if (MODE == 0) score_csr[k] = p0 + bb2;
            else           score_csr[k] += p0 + bb2;
        }
    }

    // --- GIN MLP + residual (single LDS buffer: x overwritten by t in-wave) ---
    const float epsv = 1.0f + epsp[0];
    float4 hv = *(const float4*)(h + (size_t)r * 64 + 4 * li);
    xs[row16][4*li+0] = epsv * hv.x + acc.x;
    xs[row16][4*li+1] = epsv * hv.y + acc.y;
    xs[row16][4*li+2] = epsv * hv.z + acc.z;
    xs[row16][4*li+3] = epsv * hv.w + acc.w;

    float4 t = *(const float4*)(b1 + 4 * li);
#pragma unroll
    for (int kk = 0; kk < 64; kk++) {
        float xk = xs[row16][kk];
        float4 wv = *(const float4*)(W1 + kk * 64 + 4 * li);
        t.x += xk * wv.x; t.y += xk * wv.y; t.z += xk * wv.z; t.w += xk * wv.w;
    }
    {
        float4 sc = *(const float4*)(s1 + 4 * li);
        float4 sh = *(const float4*)(sh1 + 4 * li);
        t.x = fmaxf(t.x * sc.x + sh.x, 0.f);
        t.y = fmaxf(t.y * sc.y + sh.y, 0.f);
        t.z = fmaxf(t.z * sc.z + sh.z, 0.f);
        t.w = fmaxf(t.w * sc.w + sh.w, 0.f);
    }
    xs[row16][4*li+0] = t.x; xs[row16][4*li+1] = t.y;
    xs[row16][4*li+2] = t.z; xs[row16][4*li+3] = t.w;

    float4 u = *(const float4*)(b2 + 4 * li);
#pragma unroll
    for (int kk = 0; kk < 64; kk++) {
        float tk = xs[row16][kk];
        float4 wv = *(const float4*)(W2 + kk * 64 + 4 * li);
        u.x += tk * wv.x; u.y += tk * wv.y; u.z += tk * wv.z; u.w += tk * wv.w;
    }
    {
        float4 sc = *(const float4*)(as_ + 4 * li);
        float4 sh = *(const float4*)(ash + 4 * li);
        u.x = fmaxf(u.x * sc.x + sh.x, 0.f);
        u.y = fmaxf(u.y * sc.y + sh.y, 0.f);
        u.z = fmaxf(u.z * sc.z + sh.z, 0.f);
        u.w = fmaxf(u.w * sc.w + sh.w, 0.f);
        sc = *(const float4*)(gs + 4 * li);
        sh = *(const float4*)(gsh + 4 * li);
        u.x = fmaxf(u.x * sc.x + sh.x, 0.f);
        u.y = fmaxf(u.y * sc.y + sh.y, 0.f);
        u.z = fmaxf(u.z * sc.z + sh.z, 0.f);
        u.w = fmaxf(u.w * sc.w + sh.w, 0.f);
    }
    float4 o = make_float4(hv.x + u.x, hv.y + u.y, hv.z + u.z, hv.w + u.w);
    *(float4*)(hout + (size_t)r * 64 + 4 * li) = o;

    if (EPI == 1)
        epi_tables16<1>(xs, row16, li, r, o, WAn, bAn, WBn, tab_out, B_out);
    else if (EPI == 2)
        epi_tables16<2>(xs, row16, li, r, o, WAn, bAn, WBn, tab_out, B_out);
}

// ------------- final head: score_out[eid] = relu(score_csr + pred) -----------
// COMPACT: A from compact 128B/node table; else A-half of comb (int2 strided).
template <int COMPACT>
__global__ __launch_bounds__(256) void k_head(
    const ushort_t* __restrict__ Atab,
    const ushort_t* __restrict__ Bm,
    const int4* __restrict__ entries, const int* __restrict__ offsets,
    const int* __restrict__ perm,
    const float* __restrict__ score_csr, float* __restrict__ score_out,
    const float* __restrict__ Wc, const float* __restrict__ W2v,
    const float* __restrict__ b2p, int N)
{
    const int row16 = threadIdx.x >> 4;
    const int li    = threadIdx.x & 15;
    const int idx   = blockIdx.x * 16 + row16;
    if (idx >= N) return;
    const int r = perm[idx];

    const float4 wc0 = *(const float4*)(Wc + li*4);
    const float4 wc1 = *(const float4*)(Wc + 64 + li*4);
    const float4 w2v = *(const float4*)(W2v + li*4);
    const float bb2 = b2p[0];
    ushort4 bu = *(const ushort4*)(Bm + (size_t)r * 64 + li*4);
    const float4 brow = make_float4(bf2f(bu.x), bf2f(bu.y), bf2f(bu.z), bf2f(bu.w));

    const int beg = offsets[r], end = offsets[r + 1];

#define ALOAD(s, ax, ay) { \
    if (COMPACT) { \
        ushort4 a_ = *(const ushort4*)(Atab + (size_t)(s) * 64 + li * 4); \
        ax = (uint_t)a_.x | ((uint_t)a_.y << 16); \
        ay = (uint_t)a_.z | ((uint_t)a_.w << 16); \
    } else { \
        int2 d_ = *(const int2*)(Atab + (size_t)(s) * 128 + li * 8); \
        ax = (uint_t)d_.x; ay = (uint_t)d_.y; \
    } }
#define HSCOR(kk, e_, ax, ay) { \
    float p_ = edge_p2(ax, ay, brow, __int_as_float((e_).z), __int_as_float((e_).w), \
                       wc0, wc1, w2v); \
    RED16(p_) \
    if (li == 0) score_out[(e_).y] = fmaxf(score_csr[kk] + p_ + bb2, 0.f); }

    int k = beg;
    for (; k + 3 < end; k += 4) {
        int4 e0 = entries[k], e1 = entries[k+1], e2 = entries[k+2], e3 = entries[k+3];
        uint_t ax0, ay0, ax1, ay1, ax2, ay2, ax3, ay3;
        ALOAD(e0.x, ax0, ay0) ALOAD(e1.x, ax1, ay1)
        ALOAD(e2.x, ax2, ay2) ALOAD(e3.x, ax3, ay3)
        HSCOR(k, e0, ax0, ay0) HSCOR(k+1, e1, ax1, ay1)
        HSCOR(k+2, e2, ax2, ay2) HSCOR(k+3, e3, ax3, ay3)
    }
    for (; k < end; k++) {
        int4 e0 = entries[k];
        uint_t ax0, ay0;
        ALOAD(e0.x, ax0, ay0)
        HSCOR(k, e0, ax0, ay0)
    }
#undef ALOAD
#undef HSCOR
}

extern "C" void kernel_launch(void* const* d_in, const int* in_sizes, int n_in,
                              void* d_out, int out_size, void* d_ws, size_t ws_size,
                              hipStream_t stream) {
    const float* h_in  = (const float*)d_in[0];
    const float* e     = (const float*)d_in[1];
    const int*   src   = (const int*)d_in[2];
    const int*   dst   = (const int*)d_in[3];
    const float* emb_W = (const float*)d_in[4];
    const float* emb_b = (const float*)d_in[5];
    const float* eps   = (const float*)d_in[6];
    const float* mW1   = (const float*)d_in[7];
    const float* mb1   = (const float*)d_in[8];
    const float* mbs   = (const float*)d_in[9];
    const float* mbsh  = (const float*)d_in[10];
    const float* mW2   = (const float*)d_in[11];
    const float* mb2   = (const float*)d_in[12];
    const float* as_   = (const float*)d_in[13];
    const float* ash   = (const float*)d_in[14];
    const float* gs    = (const float*)d_in[15];
    const float* gsh   = (const float*)d_in[16];
    const float* pW1   = (const float*)d_in[17];
    const float* pb1   = (const float*)d_in[18];
    const float* pW2   = (const float*)d_in[19];
    const float* pb2   = (const float*)d_in[20];

    const int N  = in_sizes[0] / 64;
    const int E  = in_sizes[2];
    const int Lr = in_sizes[6];
    const size_t nrow = (size_t)N * 64;

    float* score = (float*)d_out;

    char* wp = (char*)d_ws;
    auto take = [&](size_t b) -> char* {
        char* p = wp; wp += (b + 255) & ~(size_t)255; return p;
    };
    float*    h0        = (float*)take(nrow * 4);
    float*    h1        = (float*)take(nrow * 4);
    ushort_t* comb0     = (ushort_t*)take(nrow * 4);   // [N][128] ushort
    ushort_t* B0        = (ushort_t*)take(nrow * 2);
    int4*     entries   = (int4*)take((size_t)E * 16);
    float*    score_csr = (float*)take((size_t)E * 4);
    int*      offsets   = (int*)take((size_t)(N + 1) * 4);
    int*      cursor    = (int*)take((size_t)N * 4);
    int*      bsum      = (int*)take(1024);
    int*      perm      = (int*)take((size_t)N * 4);
    int*      bcnt      = (int*)take(64 * 4);
    int*      bcur      = (int*)take(64 * 4);
    ushort_t* comb1     = (ushort_t*)take(nrow * 4);
    ushort_t* B1        = (ushort_t*)take(nrow * 2);
    ushort_t* Afin      = (ushort_t*)take(nrow * 2);
    size_t need_epi = (size_t)(wp - (char*)d_ws);

    const bool use_epi = ws_size >= need_epi;

    const int rowBlocks = (N + 15) / 16;
    const int edgeGrid  = (E + 255) / 256;
    const int nb        = (N + 1023) / 1024;

    // ---- CSR build + degree histogram ----
    hipMemsetAsync(cursor, 0, (size_t)N * sizeof(int), stream);
    hipMemsetAsync(bcnt, 0, 64 * sizeof(int), stream);
    k_count<<<edgeGrid, 256, 0, stream>>>(dst, cursor, E);
    k_scanA<<<nb, 1024, 0, stream>>>(cursor, offsets, bsum, bcnt, N);
    k_scanB<<<1, 256, 0, stream>>>(bsum, nb, offsets + N);
    k_scanC<<<(N + 255) / 256, 256, 0, stream>>>(offsets, bsum, cursor, N);
    k_fill<<<edgeGrid, 256, 0, stream>>>(src, dst, e, cursor, entries, E);

    // ---- degree-bucket permutation (descending) ----
    k_bscan<<<1, 64, 0, stream>>>(bcnt, bcur);
    k_bfill<<<(N + 255) / 256, 256, 0, stream>>>(offsets, bcur, perm, N);

    // ---- embed + head-0 tables ----
    k_embed_ab<<<rowBlocks, 256, 0, stream>>>(
        h_in, emb_W, emb_b, h0, pW1, pb1, pW1 + 64 * 64, comb0, B0, N);

    float* hcur = h0;       float* hnext = h1;
    ushort_t* Ccur = comb0; ushort_t* Cnxt = use_epi ? comb1 : comb0;
    ushort_t* Bcur = B0;    ushort_t* Bnxt = use_epi ? B1 : B0;

    for (int i = 0; i < Lr; i++) {
        const float* pw  = pW1 + (size_t)i * 130 * 64;
        const float* Wc  = pw + 128 * 64;
        const float* w2  = pW2 + (size_t)i * 64;
        const float* b2  = pb2 + i;
        const float* pwn = pW1 + (size_t)(i + 1) * 130 * 64;
        const float* gW1 = mW1 + (size_t)i * 64 * 64;
        const float* gW2 = mW2 + (size_t)i * 64 * 64;
        const bool last = (i == Lr - 1);

        if (use_epi) {
            ushort_t* tout = last ? Afin : Cnxt;
            if (i == 0 && !last)
                k_fused<0,1><<<rowBlocks, 256, 0, stream>>>(
                    hcur, hnext, Ccur, Bcur, entries, offsets, perm, score_csr,
                    Wc, w2, b2, eps + i,
                    gW1, mb1 + i*64, mbs + i*64, mbsh + i*64, gW2, mb2 + i*64,
                    as_ + i*64, ash + i*64, gs + i*64, gsh + i*64,
                    pwn, pb1 + (i+1)*64, pwn + 64*64, tout, Bnxt, N);
            else if (i == 0 && last)
                k_fused<0,2><<<rowBlocks, 256, 0, stream>>>(
                    hcur, hnext, Ccur, Bcur, entries, offsets, perm, score_csr,
                    Wc, w2, b2, eps + i,
                    gW1, mb1 + i*64, mbs + i*64, mbsh + i*64, gW2, mb2 + i*64,
                    as_ + i*64, ash + i*64, gs + i*64, gsh + i*64,
                    pwn, pb1 + (i+1)*64, pwn + 64*64, tout, Bnxt, N);
            else if (!last)
                k_fused<1,1><<<rowBlocks, 256, 0, stream>>>(
                    hcur, hnext, Ccur, Bcur, entries, offsets, perm, score_csr,
                    Wc, w2, b2, eps + i,
                    gW1, mb1 + i*64, mbs + i*64, mbsh + i*64, gW2, mb2 + i*64,
                    as_ + i*64, ash + i*64, gs + i*64, gsh + i*64,
                    pwn, pb1 + (i+1)*64, pwn + 64*64, tout, Bnxt, N);
            else
                k_fused<1,2><<<rowBlocks, 256, 0, stream>>>(
                    hcur, hnext, Ccur, Bcur, entries, offsets, perm, score_csr,
                    Wc, w2, b2, eps + i,
                    gW1, mb1 + i*64, mbs + i*64, mbsh + i*64, gW2, mb2 + i*64,
                    as_ + i*64, ash + i*64, gs + i*64, gsh + i*64,
                    pwn, pb1 + (i+1)*64, pwn + 64*64, tout, Bnxt, N);
            { ushort_t* t = Ccur; Ccur = Cnxt; Cnxt = t; }
            { ushort_t* t = Bcur; Bcur = Bnxt; Bnxt = t; }
        } else {
            if (i == 0)
                k_fused<0,0><<<rowBlocks, 256, 0, stream>>>(
                    hcur, hnext, Ccur, Bcur, entries, offsets, perm, score_csr,
                    Wc, w2, b2, eps + i,
                    gW1, mb1 + i*64, mbs + i*64, mbsh + i*64, gW2, mb2 + i*64,
                    as_ + i*64, ash + i*64, gs + i*64, gsh + i*64,
                    nullptr, nullptr, nullptr, nullptr, nullptr, N);
            else
                k_fused<1,0><<<rowBlocks, 256, 0, stream>>>(
                    hcur, hnext, Ccur, Bcur, entries, offsets, perm, score_csr,
                    Wc, w2, b2, eps + i,
                    gW1, mb1 + i*64, mbs + i*64, mbsh + i*64, gW2, mb2 + i*64,
                    as_ + i*64, ash + i*64, gs + i*64, gsh + i*64,
                    nullptr, nullptr, nullptr, nullptr, nullptr, N);
            k_tables<<<rowBlocks, 256, 0, stream>>>(
                hnext, pwn, pb1 + (i+1)*64, pwn + 64*64, Ccur, Bcur, N);
        }
        { float* t = hcur; hcur = hnext; hnext = t; }
    }

    // ---- final head ----
    {
        const float* pw = pW1 + (size_t)Lr * 130 * 64;
        const float* Wc = pw + 128 * 64;
        const float* w2 = pW2 + (size_t)Lr * 64;
        const float* b2 = pb2 + Lr;
        if (use_epi)
            k_head<1><<<rowBlocks, 256, 0, stream>>>(
                Afin, Bcur, entries, offsets, perm, score_csr, score,
                Wc, w2, b2, N);
        else
            k_head<0><<<rowBlocks, 256, 0, stream>>>(
                Ccur, Bcur, entries, offsets, perm, score_csr, score,
                Wc, w2, b2, N);
    }
}